// Round 3
// baseline (9.424 us; speedup 1.0000x reference)
//
#include <hip/hip_runtime.h>

#define NN 8192
#define EE 256
#define LL 4
#define ROWS 8   // rows per wave

__global__ __launch_bounds__(256) void GraphFilter_kernel(
    const float* __restrict__ emb,   // N*E
    const float* __restrict__ A,     // L*N*N
    const int*   __restrict__ idp,   // 1
    const float* __restrict__ w,     // 2E
    float* __restrict__ out)         // N
{
    const int id   = idp[0];
    const int lane = threadIdx.x & 63;
    const int wv   = __builtin_amdgcn_readfirstlane((int)(threadIdx.x >> 6));
    const int j0   = (blockIdx.x * 4 + wv) * ROWS;   // first of 8 rows for this wave

    // ---- wave-uniform A loads (scalar, issued first, latency fully hidden) ----
    float asum[ROWS];
    #pragma unroll
    for (int r = 0; r < ROWS; ++r) asum[r] = 0.f;
    #pragma unroll
    for (int l = 0; l < LL; ++l) {
        const float* Ap = A + (size_t)l * NN * NN + (size_t)id * NN + j0;
        #pragma unroll
        for (int r = 0; r < ROWS; ++r) asum[r] += Ap[r];
    }

    // ---- per-lane slice (16 B) of the E=256 dot products ----
    const int e4 = lane * 4;
    const float4 w1 = *reinterpret_cast<const float4*>(w + e4);
    const float4 w2 = *reinterpret_cast<const float4*>(w + EE + e4);
    const float4 ei = *reinterpret_cast<const float4*>(emb + (size_t)id * EE + e4);

    float4 er[ROWS];
    #pragma unroll
    for (int r = 0; r < ROWS; ++r)
        er[r] = *reinterpret_cast<const float4*>(emb + (size_t)(j0 + r) * EE + e4);

    float s = ei.x * w2.x + ei.y * w2.y + ei.z * w2.z + ei.w * w2.w;
    float d[ROWS];
    #pragma unroll
    for (int r = 0; r < ROWS; ++r)
        d[r] = er[r].x * w1.x + er[r].y * w1.y + er[r].z * w1.z + er[r].w * w1.w;

    // ---- 9 independent butterfly chains, interleaved ----
    #pragma unroll
    for (int off = 32; off >= 1; off >>= 1) {
        s += __shfl_xor(s, off, 64);
        #pragma unroll
        for (int r = 0; r < ROWS; ++r) d[r] += __shfl_xor(d[r], off, 64);
    }

    if (lane == 0) {
        float o[ROWS];
        #pragma unroll
        for (int r = 0; r < ROWS; ++r) {
            const float rr = fmaxf(d[r] + s, 0.f);
            o[r] = (asum[r] != 0.0f) ? asum[r] * rr : 0.0f;
        }
        float4 o0 = {o[0], o[1], o[2], o[3]};
        float4 o1 = {o[4], o[5], o[6], o[7]};
        *reinterpret_cast<float4*>(out + j0)     = o0;
        *reinterpret_cast<float4*>(out + j0 + 4) = o1;
    }
}

extern "C" void kernel_launch(void* const* d_in, const int* in_sizes, int n_in,
                              void* d_out, int out_size, void* d_ws, size_t ws_size,
                              hipStream_t stream) {
    const float* emb = (const float*)d_in[0];
    const float* A   = (const float*)d_in[1];
    const int*   idp = (const int*)d_in[2];
    const float* w   = (const float*)d_in[3];
    float* out = (float*)d_out;

    dim3 grid(NN / (4 * ROWS));   // 256 blocks x 4 waves x 8 rows = 8192 rows
    dim3 block(256);
    GraphFilter_kernel<<<grid, block, 0, stream>>>(emb, A, idp, w, out);
}